// Round 6
// baseline (1624.191 us; speedup 1.0000x reference)
//
#include <hip/hip_runtime.h>

#define DD 256
#define BSHIFT 9            // 512 rows per bucket
#define BROWS  512
#define NBMAX  1024         // supports N up to 524288

typedef short bf16x8 __attribute__((ext_vector_type(8)));
typedef float f32x4 __attribute__((ext_vector_type(4)));

__device__ __forceinline__ float bf2f(ushort v) {
    union { uint u; float f; } c; c.u = ((uint)v) << 16; return c.f;
}
__device__ __forceinline__ ushort f2bf(float f) {
    union { float f; uint u; } c; c.f = f;
    uint u = c.u;
    u += 0x7fffu + ((u >> 16) & 1u);   // RNE
    return (ushort)(u >> 16);
}

// ------------------ dtype detection ------------------
// flags[0]=1 -> float inputs are fp32 (else bf16); flags[1]=1 -> edge_index is int64 (else int32)
__global__ __launch_bounds__(256) void detect_kernel(const ushort* __restrict__ xbits,
                                                     const int* __restrict__ ei,
                                                     int* __restrict__ flags) {
    __shared__ int cnt[2];
    int t = threadIdx.x;
    if (t < 2) cnt[t] = 0;
    __syncthreads();
    int e = (xbits[2 * t] >> 7) & 0xFF;
    if (e >= 96 && e <= 144) atomicAdd(&cnt[0], 1);
    if (t < 128 && ei[2 * t + 1] == 0) atomicAdd(&cnt[1], 1);
    __syncthreads();
    if (t == 0) {
        flags[0] = (cnt[0] < 180) ? 1 : 0;
        flags[1] = (cnt[1] > 64) ? 1 : 0;
    }
}

// ------------------ input normalization ------------------
__global__ void conv_bf_kernel(const void* __restrict__ src, ushort* __restrict__ dst,
                               int n, const int* __restrict__ flags) {
    int i = blockIdx.x * blockDim.x + threadIdx.x;
    if (i < n)
        dst[i] = flags[0] ? f2bf(((const float*)src)[i]) : ((const ushort*)src)[i];
}

__global__ void conv_f32_kernel(const void* __restrict__ src, float* __restrict__ dst,
                                int n, const int* __restrict__ flags) {
    int i = blockIdx.x * blockDim.x + threadIdx.x;
    if (i < n)
        dst[i] = flags[0] ? ((const float*)src)[i] : bf2f(((const ushort*)src)[i]);
}

// ------------------ graph setup ------------------
__device__ __forceinline__ int edge_row(const int* ei, int e, int E_, int is64) {
    return ei[is64 ? (2 * e) : e];
}
__device__ __forceinline__ int edge_col(const int* ei, int e, int E_, int is64) {
    return ei[is64 ? (2 * (E_ + e)) : (E_ + e)];
}

// Pass A0: column-degree atomics (for dinv) + per-block LDS bucket histogram ->
// one global atomicAdd per (block,bucket).
__global__ __launch_bounds__(256) void countA_kernel(
        const int* __restrict__ ei, int E_, int n,
        int* __restrict__ colcnt, int* __restrict__ bkt_cnt,
        const int* __restrict__ flags) {
    __shared__ int hist[NBMAX];
    int t = threadIdx.x;
    for (int j = t; j < NBMAX; j += 256) hist[j] = 0;
    __syncthreads();
    int is64 = flags[1];
    int b0 = blockIdx.x * 4096;
    int bend = min(b0 + 4096, E_);
    for (int i = b0 + t; i < bend; i += 256) {
        int r = edge_row(ei, i, E_, is64);
        int c = edge_col(ei, i, E_, is64);
        if ((unsigned)r < (unsigned)n && (unsigned)c < (unsigned)n) {
            atomicAdd(&colcnt[c], 1);
            atomicAdd(&hist[r >> BSHIFT], 1);
        }
    }
    __syncthreads();
    for (int j = t; j < NBMAX; j += 256)
        if (hist[j] > 0) atomicAdd(&bkt_cnt[j], hist[j]);
}

__global__ void dinv_kernel(const int* __restrict__ colcnt, float* __restrict__ dinv, int n) {
    int i = blockIdx.x * blockDim.x + threadIdx.x;
    if (i < n) {
        int c = colcnt[i];
        dinv[i] = (c > 0) ? rsqrtf((float)c) : 0.0f;
    }
}

// tiny exclusive scan over <=1024 bucket counts -> bbase (and a mutable copy gcur)
__global__ __launch_bounds__(1024) void bscan_kernel(
        const int* __restrict__ bkt_cnt, int* __restrict__ bbase,
        int* __restrict__ gcur, int nb) {
    __shared__ int lds[NBMAX];
    int t = threadIdx.x;
    int v = (t < nb) ? bkt_cnt[t] : 0;
    lds[t] = v;
    __syncthreads();
    for (int off = 1; off < NBMAX; off <<= 1) {
        int add = (t >= off) ? lds[t - off] : 0;
        __syncthreads();
        lds[t] += add;
        __syncthreads();
    }
    if (t < nb) {
        int base = lds[t] - v;   // exclusive
        bbase[t] = base;
        gcur[t]  = base;
    }
    if (t == nb - 1) bbase[nb] = lds[t];
}

// Pass A: partition edges into bucket-grouped pairs.
__global__ __launch_bounds__(256) void partition_kernel(
        const int* __restrict__ ei, int E_, int n,
        int* __restrict__ gcur, uint2* __restrict__ pairs,
        const int* __restrict__ flags) {
    __shared__ int hist[NBMAX];
    __shared__ int base[NBMAX];
    int t = threadIdx.x;
    for (int j = t; j < NBMAX; j += 256) hist[j] = 0;
    __syncthreads();
    int is64 = flags[1];
    int b0 = blockIdx.x * 4096;
    int bend = min(b0 + 4096, E_);
    for (int i = b0 + t; i < bend; i += 256) {
        int r = edge_row(ei, i, E_, is64);
        int c = edge_col(ei, i, E_, is64);
        if ((unsigned)r < (unsigned)n && (unsigned)c < (unsigned)n)
            atomicAdd(&hist[r >> BSHIFT], 1);
    }
    __syncthreads();
    for (int j = t; j < NBMAX; j += 256) {
        int h = hist[j];
        base[j] = h ? atomicAdd(&gcur[j], h) : 0;
        hist[j] = 0;                       // reuse as running cursor
    }
    __syncthreads();
    for (int i = b0 + t; i < bend; i += 256) {   // ei window L2-hot from 1st loop
        int r = edge_row(ei, i, E_, is64);
        int c = edge_col(ei, i, E_, is64);
        if ((unsigned)r < (unsigned)n && (unsigned)c < (unsigned)n) {
            int bk = r >> BSHIFT;
            int pos = base[bk] + atomicAdd(&hist[bk], 1);
            if ((unsigned)pos < (unsigned)E_)    // defensive: cannot fault
                pairs[pos] = make_uint2((uint)r, (uint)c);
        }
    }
}

// Pass B: one 1024-thread block per 512-row bucket -> rowptr + csr.
__global__ __launch_bounds__(1024) void place_kernel(
        const uint2* __restrict__ pairs, const int* __restrict__ bbase,
        int nb, int n, int E_, int* __restrict__ rowptr, int* __restrict__ csr) {
    __shared__ int hist[BROWS];
    __shared__ int scn[BROWS];
    __shared__ int cur[BROWS];
    int b = blockIdx.x;
    int t = threadIdx.x;
    int r0 = b << BSHIFT;
    int rows = min(BROWS, n - r0);
    int beg = bbase[b], end = bbase[b + 1];
    if (t < BROWS) hist[t] = 0;
    __syncthreads();
    for (int i = beg + t; i < end; i += 1024) {
        int lr = (int)pairs[i].x - r0;
        if ((unsigned)lr < (unsigned)BROWS) atomicAdd(&hist[lr], 1);
    }
    __syncthreads();
    int v = (t < BROWS) ? hist[t] : 0;
    if (t < BROWS) scn[t] = v;
    __syncthreads();
    for (int off = 1; off < BROWS; off <<= 1) {
        int add = (t < BROWS && t >= off) ? scn[t - off] : 0;
        __syncthreads();
        if (t < BROWS) scn[t] += add;
        __syncthreads();
    }
    if (t < rows) rowptr[r0 + t] = beg + scn[t] - v;   // exclusive prefix
    if (b == nb - 1 && t == 0) rowptr[n] = end;
    if (t < BROWS) cur[t] = scn[t] - v;
    __syncthreads();
    for (int i = beg + t; i < end; i += 1024) {        // pairs region L2-hot
        uint2 p = pairs[i];
        int lr = (int)p.x - r0;
        if ((unsigned)lr < (unsigned)BROWS) {
            int local = atomicAdd(&cur[lr], 1);
            int pos = beg + local;
            if ((unsigned)pos < (unsigned)E_)          // defensive: cannot fault
                csr[pos] = (int)p.y;
        }
    }
}

__global__ void transpose_kernel(const ushort* __restrict__ M, ushort* __restrict__ Mt, int kdim) {
    int i = blockIdx.x * blockDim.x + threadIdx.x;
    if (i < kdim * DD) {
        int k = i >> 8, d = i & 255;
        Mt[(size_t)d * kdim + k] = M[i];
    }
}

// ------------------ Laplacian neighbor aggregate: agg[r] = sum_c dinv[c]*x[c] ------------------
__global__ __launch_bounds__(256) void lap_kernel(
    const ushort* __restrict__ xin,
    const int* __restrict__ rowptr, const int* __restrict__ csr,
    const float* __restrict__ dinv,
    ushort* __restrict__ agg, int n)
{
    __shared__ int   sc[256];
    __shared__ float sw[256];
    __shared__ float sacc[8][256];   // 8 KB

    int r = blockIdx.x;
    int t = threadIdx.x;
    int slot = t >> 5, sub = t & 31;   // 8 slots x 32 lanes
    int beg = rowptr[r], end = rowptr[r + 1];
    int deg = (end > beg) ? (end - beg) : 0;

    float acc[8];
#pragma unroll
    for (int q = 0; q < 8; ++q) acc[q] = 0.0f;

    for (int base = 0; base < deg; base += 256) {
        int nb = min(256, deg - base);
        __syncthreads();                       // protect sc/sw reuse
        if (t < nb) {
            int c = csr[beg + base + t];
            if ((unsigned)c >= (unsigned)n) c = 0;  // safety (shouldn't happen)
            sc[t] = c;
            sw[t] = dinv[c];
        }
        __syncthreads();
        for (int j = slot; j < nb; j += 8) {
            int c = sc[j];
            float wgt = sw[j];
            bf16x8 v = *(const bf16x8*)(xin + (size_t)c * DD + sub * 8);
#pragma unroll
            for (int q = 0; q < 8; ++q) acc[q] += wgt * bf2f((ushort)v[q]);
        }
    }

    // reduce across the 8 slots
#pragma unroll
    for (int q = 0; q < 8; ++q) sacc[slot][sub * 8 + q] = acc[q];
    __syncthreads();
    float s = 0.0f;
#pragma unroll
    for (int q = 0; q < 8; ++q) s += sacc[q][t];
    agg[(size_t)r * DD + t] = f2bf(s);
}

// ------------------ fused Hopfield attention + blend + LayerNorm ------------------
// out[r] = LN( 0.5*x[r] + 0.5*( softmax(x M^T) M - 0.2*(x[r] - dinv[r]*agg[r]) ) )
// v6 = v5 + prefetch-to-registers (T14 async-STAGE split): chunk nb+1's 8
// global loads are ISSUED before computing chunk nb, so their L2 latency
// hides under the MFMA phase; between the two barriers only the ds_writes
// remain (~100cy, was issue+L2-latency+write). Everything else identical
// to v5 (verified): 128 rows/block, 4 waves x 2 tiles, LDS staging + Pl
// wave-private handoff via s_waitcnt lgkmcnt(0) + sched_barrier.
// A-layout: A[m=lane&15][k=quad*8+j]; B-layout: B[k=quad*8+j][n=lane&15];
// C/D: col=lane&15, row=quad*4+reg.  (m89/m120-verified mappings)
__global__ __launch_bounds__(256, 2) void attn_fused_kernel(
    const ushort* __restrict__ x, const ushort* __restrict__ M,
    const ushort* __restrict__ Mt, const ushort* __restrict__ agg,
    const float* __restrict__ dinv,
    const float* __restrict__ gf, const float* __restrict__ bfa,
    void* __restrict__ out, int nrows, int kdim,
    int final_stage, const int* __restrict__ flags)
{
    __shared__ __align__(16) ushort Ml[32][DD + 8];        // M chunk, row-major [slot][d]
    __shared__ __align__(16) ushort Mtl[DD][32 + 8];       // M^T chunk, [d][slot]
    __shared__ __align__(16) ushort Pl[4][2][16][32 + 8];  // per-wave, per-half P bounce

    const int tid  = threadIdx.x;
    const int wave = tid >> 6, lane = tid & 63;
    const int quad = lane >> 4, l16 = lane & 15;
    const int base_row = blockIdx.x * 128;
    const int write_f32 = final_stage ? flags[0] : 0;

    bf16x8 afrag[2][8];
#pragma unroll
    for (int h = 0; h < 2; ++h) {
        int r = base_row + h * 64 + wave * 16 + l16;
        if (r < nrows) {
            const bf16x8* xr = (const bf16x8*)(x + (size_t)r * DD);
#pragma unroll
            for (int c = 0; c < 8; ++c) afrag[h][c] = xr[c * 4 + quad];
        } else {
#pragma unroll
            for (int c = 0; c < 8; ++c) afrag[h][c] = (bf16x8){0,0,0,0,0,0,0,0};
        }
    }

    float lsum[2][4];
#pragma unroll
    for (int h = 0; h < 2; ++h)
#pragma unroll
        for (int rg = 0; rg < 4; ++rg) lsum[h][rg] = 0.f;
    f32x4 O0[16], O1[16];
#pragma unroll
    for (int i = 0; i < 16; ++i) { O0[i] = (f32x4){0.f,0.f,0.f,0.f}; O1[i] = (f32x4){0.f,0.f,0.f,0.f}; }

    const int nblk = kdim >> 5;

    // staging registers: 8 x uint4 (32 VGPRs)
    uint4 sreg[8];

    // prologue: load + write chunk 0
#pragma unroll
    for (int it = 0; it < 4; ++it) {
        int i = tid + it * 256;
        int rr = i >> 5, cc = i & 31;
        sreg[it] = *(const uint4*)(M + (size_t)(0 * 32 + rr) * DD + cc * 8);
    }
#pragma unroll
    for (int it = 0; it < 4; ++it) {
        int i = tid + it * 256;
        int rr = i >> 2, cc = i & 3;
        sreg[4 + it] = *(const uint4*)(Mt + (size_t)rr * kdim + 0 * 32 + cc * 8);
    }
#pragma unroll
    for (int it = 0; it < 4; ++it) {
        int i = tid + it * 256;
        int rr = i >> 5, cc = i & 31;
        *(uint4*)&Ml[rr][cc * 8] = sreg[it];
    }
#pragma unroll
    for (int it = 0; it < 4; ++it) {
        int i = tid + it * 256;
        int rr = i >> 2, cc = i & 3;
        *(uint4*)&Mtl[rr][cc * 8] = sreg[4 + it];
    }

    for (int nb = 0; nb < nblk; ++nb) {
        __syncthreads();   // staged chunk nb visible to all waves
        const bool pf = (nb + 1 < nblk);
        if (pf) {
            // issue chunk nb+1 loads NOW; latency hides under compute below
#pragma unroll
            for (int it = 0; it < 4; ++it) {
                int i = tid + it * 256;
                int rr = i >> 5, cc = i & 31;
                sreg[it] = *(const uint4*)(M + (size_t)((nb + 1) * 32 + rr) * DD + cc * 8);
            }
#pragma unroll
            for (int it = 0; it < 4; ++it) {
                int i = tid + it * 256;
                int rr = i >> 2, cc = i & 3;
                sreg[4 + it] = *(const uint4*)(Mt + (size_t)rr * kdim + (nb + 1) * 32 + cc * 8);
            }
        }

        // scores S[2][16 x 32] = x_tile . M_chunk^T; each b feeds both halves
#pragma unroll
        for (int cc = 0; cc < 2; ++cc) {
            f32x4 s0 = (f32x4){0.f,0.f,0.f,0.f};
            f32x4 s1 = (f32x4){0.f,0.f,0.f,0.f};
#pragma unroll
            for (int ds = 0; ds < 8; ++ds) {
                bf16x8 b = *(const bf16x8*)&Ml[cc * 16 + l16][ds * 32 + quad * 8];
                s0 = __builtin_amdgcn_mfma_f32_16x16x32_bf16(afrag[0][ds], b, s0, 0, 0, 0);
                s1 = __builtin_amdgcn_mfma_f32_16x16x32_bf16(afrag[1][ds], b, s1, 0, 0, 0);
            }
#pragma unroll
            for (int rg = 0; rg < 4; ++rg) {
                float p0 = __expf(s0[rg]);
                float p1 = __expf(s1[rg]);
                lsum[0][rg] += p0;
                lsum[1][rg] += p1;
                Pl[wave][0][quad * 4 + rg][cc * 16 + l16] = f2bf(p0);
                Pl[wave][1][quad * 4 + rg][cc * 16 + l16] = f2bf(p1);
            }
        }
        // wave-private handoff: Pl is wave-indexed, no block barrier needed.
        asm volatile("s_waitcnt lgkmcnt(0)" ::: "memory");
        __builtin_amdgcn_sched_barrier(0);
        bf16x8 pa0 = *(const bf16x8*)&Pl[wave][0][l16][quad * 8];
        bf16x8 pa1 = *(const bf16x8*)&Pl[wave][1][l16][quad * 8];
        // O += P[16x32] . M_chunk[32x256]; each b feeds both halves
#pragma unroll
        for (int f = 0; f < 16; ++f) {
            bf16x8 b = *(const bf16x8*)&Mtl[f * 16 + l16][quad * 8];
            O0[f] = __builtin_amdgcn_mfma_f32_16x16x32_bf16(pa0, b, O0[f], 0, 0, 0);
            O1[f] = __builtin_amdgcn_mfma_f32_16x16x32_bf16(pa1, b, O1[f], 0, 0, 0);
        }

        __syncthreads();   // all waves done reading Ml/Mtl for chunk nb
        if (pf) {
            // regs ready by now (latency covered by compute); write next chunk
#pragma unroll
            for (int it = 0; it < 4; ++it) {
                int i = tid + it * 256;
                int rr = i >> 5, cc = i & 31;
                *(uint4*)&Ml[rr][cc * 8] = sreg[it];
            }
#pragma unroll
            for (int it = 0; it < 4; ++it) {
                int i = tid + it * 256;
                int rr = i >> 2, cc = i & 3;
                *(uint4*)&Mtl[rr][cc * 8] = sreg[4 + it];
            }
        }
    }

    // ---- epilogue per half: denom reduce + blend + LayerNorm (row-local, in-place safe) ----
    float gcol[16], bcol[16];
#pragma unroll
    for (int f = 0; f < 16; ++f) {
        gcol[f] = gf[f * 16 + l16];
        bcol[f] = bfa[f * 16 + l16];
    }
#pragma unroll
    for (int h = 0; h < 2; ++h) {
        float l_r[4];
#pragma unroll
        for (int rg = 0; rg < 4; ++rg) {
            float v = lsum[h][rg];
#pragma unroll
            for (int off = 1; off < 16; off <<= 1) v += __shfl_xor(v, off);
            l_r[rg] = v;
        }
#pragma unroll
        for (int rg = 0; rg < 4; ++rg) {
            int grow = base_row + h * 64 + wave * 16 + quad * 4 + rg;
            if (grow < nrows) {
                float inv = 1.0f / l_r[rg];
                float dr  = dinv[grow];
                const ushort* xp = x   + (size_t)grow * DD;
                const ushort* ap = agg + (size_t)grow * DD;
                float xn[16];
                float s = 0.0f;
#pragma unroll
                for (int f = 0; f < 16; ++f) {
                    float xr  = bf2f(xp[f * 16 + l16]);
                    float ag  = bf2f(ap[f * 16 + l16]);
                    float rv  = (h ? O1[f][rg] : O0[f][rg]) * inv;
                    float lap = xr - dr * ag;                     // x - D^-1/2 A D^-1/2 x
                    float v   = 0.5f * xr + 0.5f * (rv - 0.2f * lap);
                    xn[f] = v;
                    s += v;
                }
#pragma unroll
                for (int off = 1; off < 16; off <<= 1) s += __shfl_xor(s, off);
                float mu = s * (1.0f / 256.0f);
                float vs = 0.0f;
#pragma unroll
                for (int f = 0; f < 16; ++f) { float d = xn[f] - mu; vs += d * d; }
#pragma unroll
                for (int off = 1; off < 16; off <<= 1) vs += __shfl_xor(vs, off);
                float rstd = rsqrtf(vs * (1.0f / 256.0f) + 1e-5f);
                if (write_f32) {
                    float* op = (float*)out + (size_t)grow * DD;
#pragma unroll
                    for (int f = 0; f < 16; ++f)
                        op[f * 16 + l16] = (xn[f] - mu) * rstd * gcol[f] + bcol[f];
                } else {
                    ushort* op = (ushort*)out + (size_t)grow * DD;
#pragma unroll
                    for (int f = 0; f < 16; ++f)
                        op[f * 16 + l16] = f2bf((xn[f] - mu) * rstd * gcol[f] + bcol[f]);
                }
            }
        }
    }
}

// ------------------ launch ------------------
extern "C" void kernel_launch(void* const* d_in, const int* in_sizes, int n_in,
                              void* d_out, int out_size, void* d_ws, size_t ws_size,
                              hipStream_t stream)
{
    const void* x_raw = d_in[0];
    const int*  ei    = (const int*)d_in[1];
    const void* M_raw = d_in[2];
    const void* g_raw = d_in[3];
    const void* b_raw = d_in[4];

    const int N_ = in_sizes[0] / DD;
    const int E_ = in_sizes[1] / 2;
    const int K_ = in_sizes[2] / DD;
    const int NB_ = (N_ + BROWS - 1) >> BSHIFT;

    char* w = (char*)d_ws;
    size_t off = 0;
    auto alloc = [&](size_t bytes) -> char* {
        char* p = w + off;
        off = (off + bytes + 255) & ~(size_t)255;
        return p;
    };
    ushort* xbf     = (ushort*)alloc((size_t)N_ * DD * 2);   // 51.2 MB
    ushort* agg     = (ushort*)alloc((size_t)N_ * DD * 2);   // 51.2 MB
    int*    csr     = (int*)   alloc((size_t)E_ * 4);        // 12.8 MB
    ushort* Mbf     = (ushort*)alloc((size_t)K_ * DD * 2);
    ushort* Mt      = (ushort*)alloc((size_t)K_ * DD * 2);
    float*  dinv    = (float*) alloc((size_t)N_ * 4);
    int*    colcnt  = (int*)   alloc((size_t)N_ * 4);
    int*    rowptr  = (int*)   alloc((size_t)(N_ + 1) * 4);
    float*  gf      = (float*) alloc((size_t)DD * 4);
    float*  bfa     = (float*) alloc((size_t)DD * 4);
    int*    flags   = (int*)   alloc(256);
    int*    bkt_cnt = (int*)   alloc((size_t)NBMAX * 4);
    int*    bbase   = (int*)   alloc((size_t)(NBMAX + 1) * 4);
    int*    gcur    = (int*)   alloc((size_t)NBMAX * 4);

    // pairs buffer (E*8B = 25.6MB) overlays agg (51.2MB): agg is dead until
    // lap_kernel, which runs after place_kernel completes (same stream).
    uint2* pairs = (uint2*)agg;

    hipMemsetAsync(colcnt, 0, (size_t)N_ * 4, stream);
    hipMemsetAsync(bkt_cnt, 0, (size_t)NBMAX * 4, stream);

    detect_kernel<<<1, 256, 0, stream>>>((const ushort*)x_raw, ei, flags);

    int nx = N_ * DD, nm = K_ * DD;
    conv_bf_kernel<<<(nx + 255) / 256, 256, 0, stream>>>(x_raw, xbf, nx, flags);
    conv_bf_kernel<<<(nm + 255) / 256, 256, 0, stream>>>(M_raw, Mbf, nm, flags);
    conv_f32_kernel<<<1, 256, 0, stream>>>(g_raw, gf, DD, flags);
    conv_f32_kernel<<<1, 256, 0, stream>>>(b_raw, bfa, DD, flags);
    transpose_kernel<<<(nm + 255) / 256, 256, 0, stream>>>(Mbf, Mt, K_);

    int gA = (E_ + 4095) / 4096;
    int gN = (N_ + 255) / 256;
    countA_kernel<<<gA, 256, 0, stream>>>(ei, E_, N_, colcnt, bkt_cnt, flags);
    dinv_kernel<<<gN, 256, 0, stream>>>(colcnt, dinv, N_);
    bscan_kernel<<<1, NBMAX, 0, stream>>>(bkt_cnt, bbase, gcur, NB_);
    partition_kernel<<<gA, 256, 0, stream>>>(ei, E_, N_, gcur, pairs, flags);
    place_kernel<<<NB_, 1024, 0, stream>>>(pairs, bbase, NB_, N_, E_, rowptr, csr);

    int attnBlocks = (N_ + 127) / 128;
    // iteration 1: xbf -> xbf (in place; attention is row-local)
    lap_kernel<<<N_, 256, 0, stream>>>(xbf, rowptr, csr, dinv, agg, N_);
    attn_fused_kernel<<<attnBlocks, 256, 0, stream>>>(xbf, Mbf, Mt, agg, dinv, gf, bfa,
                                                      (void*)xbf, N_, K_, 0, flags);
    // iteration 2: xbf -> d_out (final dtype per flag)
    lap_kernel<<<N_, 256, 0, stream>>>(xbf, rowptr, csr, dinv, agg, N_);
    attn_fused_kernel<<<attnBlocks, 256, 0, stream>>>(xbf, Mbf, Mt, agg, dinv, gf, bfa,
                                                      d_out, N_, K_, 1, flags);
}

// Round 7
// 1218.227 us; speedup vs baseline: 1.3332x; 1.3332x over previous
//
#include <hip/hip_runtime.h>

#define DD 256
#define BSHIFT 9            // 512 rows per bucket
#define BROWS  512
#define NBMAX  1024         // supports N up to 524288

typedef short bf16x8 __attribute__((ext_vector_type(8)));
typedef float f32x4 __attribute__((ext_vector_type(4)));

__device__ __forceinline__ float bf2f(ushort v) {
    union { uint u; float f; } c; c.u = ((uint)v) << 16; return c.f;
}
__device__ __forceinline__ ushort f2bf(float f) {
    union { float f; uint u; } c; c.f = f;
    uint u = c.u;
    u += 0x7fffu + ((u >> 16) & 1u);   // RNE
    return (ushort)(u >> 16);
}

// async global->LDS, 16B per lane; LDS dest = wave-uniform base + lane*16
__device__ __forceinline__ void glds16(const void* g, void* l) {
    __builtin_amdgcn_global_load_lds(
        (const __attribute__((address_space(1))) void*)g,
        (__attribute__((address_space(3))) void*)l, 16, 0, 0);
}

// ------------------ dtype detection ------------------
// flags[0]=1 -> float inputs are fp32 (else bf16); flags[1]=1 -> edge_index is int64 (else int32)
__global__ __launch_bounds__(256) void detect_kernel(const ushort* __restrict__ xbits,
                                                     const int* __restrict__ ei,
                                                     int* __restrict__ flags) {
    __shared__ int cnt[2];
    int t = threadIdx.x;
    if (t < 2) cnt[t] = 0;
    __syncthreads();
    int e = (xbits[2 * t] >> 7) & 0xFF;
    if (e >= 96 && e <= 144) atomicAdd(&cnt[0], 1);
    if (t < 128 && ei[2 * t + 1] == 0) atomicAdd(&cnt[1], 1);
    __syncthreads();
    if (t == 0) {
        flags[0] = (cnt[0] < 180) ? 1 : 0;
        flags[1] = (cnt[1] > 64) ? 1 : 0;
    }
}

// ------------------ input normalization ------------------
__global__ void conv_bf_kernel(const void* __restrict__ src, ushort* __restrict__ dst,
                               int n, const int* __restrict__ flags) {
    int i = blockIdx.x * blockDim.x + threadIdx.x;
    if (i < n)
        dst[i] = flags[0] ? f2bf(((const float*)src)[i]) : ((const ushort*)src)[i];
}

__global__ void conv_f32_kernel(const void* __restrict__ src, float* __restrict__ dst,
                                int n, const int* __restrict__ flags) {
    int i = blockIdx.x * blockDim.x + threadIdx.x;
    if (i < n)
        dst[i] = flags[0] ? ((const float*)src)[i] : bf2f(((const ushort*)src)[i]);
}

// ------------------ graph setup ------------------
__device__ __forceinline__ int edge_row(const int* ei, int e, int E_, int is64) {
    return ei[is64 ? (2 * e) : e];
}
__device__ __forceinline__ int edge_col(const int* ei, int e, int E_, int is64) {
    return ei[is64 ? (2 * (E_ + e)) : (E_ + e)];
}

// Pass A0: column-degree atomics (for dinv) + per-block LDS bucket histogram ->
// one global atomicAdd per (block,bucket).
__global__ __launch_bounds__(256) void countA_kernel(
        const int* __restrict__ ei, int E_, int n,
        int* __restrict__ colcnt, int* __restrict__ bkt_cnt,
        const int* __restrict__ flags) {
    __shared__ int hist[NBMAX];
    int t = threadIdx.x;
    for (int j = t; j < NBMAX; j += 256) hist[j] = 0;
    __syncthreads();
    int is64 = flags[1];
    int b0 = blockIdx.x * 4096;
    int bend = min(b0 + 4096, E_);
    for (int i = b0 + t; i < bend; i += 256) {
        int r = edge_row(ei, i, E_, is64);
        int c = edge_col(ei, i, E_, is64);
        if ((unsigned)r < (unsigned)n && (unsigned)c < (unsigned)n) {
            atomicAdd(&colcnt[c], 1);
            atomicAdd(&hist[r >> BSHIFT], 1);
        }
    }
    __syncthreads();
    for (int j = t; j < NBMAX; j += 256)
        if (hist[j] > 0) atomicAdd(&bkt_cnt[j], hist[j]);
}

__global__ void dinv_kernel(const int* __restrict__ colcnt, float* __restrict__ dinv, int n) {
    int i = blockIdx.x * blockDim.x + threadIdx.x;
    if (i < n) {
        int c = colcnt[i];
        dinv[i] = (c > 0) ? rsqrtf((float)c) : 0.0f;
    }
}

// tiny exclusive scan over <=1024 bucket counts -> bbase (and a mutable copy gcur)
__global__ __launch_bounds__(1024) void bscan_kernel(
        const int* __restrict__ bkt_cnt, int* __restrict__ bbase,
        int* __restrict__ gcur, int nb) {
    __shared__ int lds[NBMAX];
    int t = threadIdx.x;
    int v = (t < nb) ? bkt_cnt[t] : 0;
    lds[t] = v;
    __syncthreads();
    for (int off = 1; off < NBMAX; off <<= 1) {
        int add = (t >= off) ? lds[t - off] : 0;
        __syncthreads();
        lds[t] += add;
        __syncthreads();
    }
    if (t < nb) {
        int base = lds[t] - v;   // exclusive
        bbase[t] = base;
        gcur[t]  = base;
    }
    if (t == nb - 1) bbase[nb] = lds[t];
}

// Pass A: partition edges into bucket-grouped pairs.
__global__ __launch_bounds__(256) void partition_kernel(
        const int* __restrict__ ei, int E_, int n,
        int* __restrict__ gcur, uint2* __restrict__ pairs,
        const int* __restrict__ flags) {
    __shared__ int hist[NBMAX];
    __shared__ int base[NBMAX];
    int t = threadIdx.x;
    for (int j = t; j < NBMAX; j += 256) hist[j] = 0;
    __syncthreads();
    int is64 = flags[1];
    int b0 = blockIdx.x * 4096;
    int bend = min(b0 + 4096, E_);
    for (int i = b0 + t; i < bend; i += 256) {
        int r = edge_row(ei, i, E_, is64);
        int c = edge_col(ei, i, E_, is64);
        if ((unsigned)r < (unsigned)n && (unsigned)c < (unsigned)n)
            atomicAdd(&hist[r >> BSHIFT], 1);
    }
    __syncthreads();
    for (int j = t; j < NBMAX; j += 256) {
        int h = hist[j];
        base[j] = h ? atomicAdd(&gcur[j], h) : 0;
        hist[j] = 0;                       // reuse as running cursor
    }
    __syncthreads();
    for (int i = b0 + t; i < bend; i += 256) {   // ei window L2-hot from 1st loop
        int r = edge_row(ei, i, E_, is64);
        int c = edge_col(ei, i, E_, is64);
        if ((unsigned)r < (unsigned)n && (unsigned)c < (unsigned)n) {
            int bk = r >> BSHIFT;
            int pos = base[bk] + atomicAdd(&hist[bk], 1);
            if ((unsigned)pos < (unsigned)E_)    // defensive: cannot fault
                pairs[pos] = make_uint2((uint)r, (uint)c);
        }
    }
}

// Pass B: one 1024-thread block per 512-row bucket -> rowptr + csr.
__global__ __launch_bounds__(1024) void place_kernel(
        const uint2* __restrict__ pairs, const int* __restrict__ bbase,
        int nb, int n, int E_, int* __restrict__ rowptr, int* __restrict__ csr) {
    __shared__ int hist[BROWS];
    __shared__ int scn[BROWS];
    __shared__ int cur[BROWS];
    int b = blockIdx.x;
    int t = threadIdx.x;
    int r0 = b << BSHIFT;
    int rows = min(BROWS, n - r0);
    int beg = bbase[b], end = bbase[b + 1];
    if (t < BROWS) hist[t] = 0;
    __syncthreads();
    for (int i = beg + t; i < end; i += 1024) {
        int lr = (int)pairs[i].x - r0;
        if ((unsigned)lr < (unsigned)BROWS) atomicAdd(&hist[lr], 1);
    }
    __syncthreads();
    int v = (t < BROWS) ? hist[t] : 0;
    if (t < BROWS) scn[t] = v;
    __syncthreads();
    for (int off = 1; off < BROWS; off <<= 1) {
        int add = (t < BROWS && t >= off) ? scn[t - off] : 0;
        __syncthreads();
        if (t < BROWS) scn[t] += add;
        __syncthreads();
    }
    if (t < rows) rowptr[r0 + t] = beg + scn[t] - v;   // exclusive prefix
    if (b == nb - 1 && t == 0) rowptr[n] = end;
    if (t < BROWS) cur[t] = scn[t] - v;
    __syncthreads();
    for (int i = beg + t; i < end; i += 1024) {        // pairs region L2-hot
        uint2 p = pairs[i];
        int lr = (int)p.x - r0;
        if ((unsigned)lr < (unsigned)BROWS) {
            int local = atomicAdd(&cur[lr], 1);
            int pos = beg + local;
            if ((unsigned)pos < (unsigned)E_)          // defensive: cannot fault
                csr[pos] = (int)p.y;
        }
    }
}

__global__ void transpose_kernel(const ushort* __restrict__ M, ushort* __restrict__ Mt, int kdim) {
    int i = blockIdx.x * blockDim.x + threadIdx.x;
    if (i < kdim * DD) {
        int k = i >> 8, d = i & 255;
        Mt[(size_t)d * kdim + k] = M[i];
    }
}

// ------------------ Laplacian neighbor aggregate: agg[r] = sum_c dinv[c]*x[c] ------------------
__global__ __launch_bounds__(256) void lap_kernel(
    const ushort* __restrict__ xin,
    const int* __restrict__ rowptr, const int* __restrict__ csr,
    const float* __restrict__ dinv,
    ushort* __restrict__ agg, int n)
{
    __shared__ int   sc[256];
    __shared__ float sw[256];
    __shared__ float sacc[8][256];   // 8 KB

    int r = blockIdx.x;
    int t = threadIdx.x;
    int slot = t >> 5, sub = t & 31;   // 8 slots x 32 lanes
    int beg = rowptr[r], end = rowptr[r + 1];
    int deg = (end > beg) ? (end - beg) : 0;

    float acc[8];
#pragma unroll
    for (int q = 0; q < 8; ++q) acc[q] = 0.0f;

    for (int base = 0; base < deg; base += 256) {
        int nb = min(256, deg - base);
        __syncthreads();                       // protect sc/sw reuse
        if (t < nb) {
            int c = csr[beg + base + t];
            if ((unsigned)c >= (unsigned)n) c = 0;  // safety (shouldn't happen)
            sc[t] = c;
            sw[t] = dinv[c];
        }
        __syncthreads();
        for (int j = slot; j < nb; j += 8) {
            int c = sc[j];
            float wgt = sw[j];
            bf16x8 v = *(const bf16x8*)(xin + (size_t)c * DD + sub * 8);
#pragma unroll
            for (int q = 0; q < 8; ++q) acc[q] += wgt * bf2f((ushort)v[q]);
        }
    }

    // reduce across the 8 slots
#pragma unroll
    for (int q = 0; q < 8; ++q) sacc[slot][sub * 8 + q] = acc[q];
    __syncthreads();
    float s = 0.0f;
#pragma unroll
    for (int q = 0; q < 8; ++q) s += sacc[q][t];
    agg[(size_t)r * DD + t] = f2bf(s);
}

// ------------------ fused Hopfield attention + blend + LayerNorm ------------------
// out[r] = LN( 0.5*x[r] + 0.5*( softmax(x M^T) M - 0.2*(x[r] - dinv[r]*agg[r]) ) )
// v7 = v5 structure + async pipeline:
//  * global_load_lds (16B) stages M/Mt chunks directly into LDS — no data VGPRs,
//    so no v6-style scratch spills. Staging map thread i -> 16B slot i is linear,
//    which is exactly glds's required dest pattern.
//  * LDS double-buffer (2x16KB Ml + 2x16KB Mtl + 10KB Pl = 74KB): issue chunk
//    nb+1's 8 glds, compute chunk nb, ONE __syncthreads (its implicit
//    vmcnt/lgkmcnt drain is the pipeline wait). Stage latency hides under MFMAs.
//  * glds can't pad, so bank conflicts fixed T21-style: linear LDS + inverse-
//    swizzled GLOBAL source + XOR-swizzled reads.
//    Ml: slot i sources col (i&31)^((i>>5)&7); reads XOR (l16&7)<<4.
//    Mtl: slot i sources col (i&3)^((i>>3)&3); reads XOR ((l16>>1)&3)<<4.
//    Both give 2-way (free) conflicts per 16-lane phase group vs 16-way linear.
// A-layout: A[m=lane&15][k=quad*8+j]; B-layout: B[k=quad*8+j][n=lane&15];
// C/D: col=lane&15, row=quad*4+reg.  (m89/m120-verified mappings)
__global__ __launch_bounds__(256, 2) void attn_fused_kernel(
    const ushort* __restrict__ x, const ushort* __restrict__ M,
    const ushort* __restrict__ Mt, const ushort* __restrict__ agg,
    const float* __restrict__ dinv,
    const float* __restrict__ gf, const float* __restrict__ bfa,
    void* __restrict__ out, int nrows, int kdim,
    int final_stage, const int* __restrict__ flags)
{
    __shared__ __align__(16) ushort Mlb[2][32 * 256];      // 2 x 16KB, linear
    __shared__ __align__(16) ushort Mtb[2][256 * 32];      // 2 x 16KB, linear
    __shared__ __align__(16) ushort Pl[4][2][16][32 + 8];  // per-wave P bounce, 10KB

    const int tid  = threadIdx.x;
    const int wave = tid >> 6, lane = tid & 63;
    const int quad = lane >> 4, l16 = lane & 15;
    const int base_row = blockIdx.x * 128;
    const int write_f32 = final_stage ? flags[0] : 0;

    bf16x8 afrag[2][8];
#pragma unroll
    for (int h = 0; h < 2; ++h) {
        int r = base_row + h * 64 + wave * 16 + l16;
        if (r < nrows) {
            const bf16x8* xr = (const bf16x8*)(x + (size_t)r * DD);
#pragma unroll
            for (int c = 0; c < 8; ++c) afrag[h][c] = xr[c * 4 + quad];
        } else {
#pragma unroll
            for (int c = 0; c < 8; ++c) afrag[h][c] = (bf16x8){0,0,0,0,0,0,0,0};
        }
    }

    float lsum[2][4];
#pragma unroll
    for (int h = 0; h < 2; ++h)
#pragma unroll
        for (int rg = 0; rg < 4; ++rg) lsum[h][rg] = 0.f;
    f32x4 O0[16], O1[16];
#pragma unroll
    for (int i = 0; i < 16; ++i) { O0[i] = (f32x4){0.f,0.f,0.f,0.f}; O1[i] = (f32x4){0.f,0.f,0.f,0.f}; }

    // ---- staging geometry (thread i -> 16B slot i, inverse-swizzled source) ----
    const int r0  = tid >> 5;                         // Ml row within chunk (it adds 8)
    const int cA  = (tid & 31) ^ (r0 & 7);            // Ml source col slot
    const int rr0 = tid >> 2;                         // Mt row (d) (it adds 64)
    const int cB  = (tid & 3) ^ ((tid >> 3) & 3);     // Mt source col slot
    const ushort* gA0 = M  + (size_t)r0 * DD + cA * 8;
    const ushort* gB0 = Mt + (size_t)rr0 * kdim + cB * 8;
    const int ldsOff = (wave * 64) * 8;               // ushort index of wave's lane0 slot

    // read-side swizzle constants (byte XOR)
    const int xorA = (l16 & 7) << 4;
    const int xorB = ((l16 >> 1) & 3) << 4;

    const int nblk = kdim >> 5;

#define STAGE(bsel, cnb)                                                          \
    {                                                                             \
        _Pragma("unroll")                                                         \
        for (int it = 0; it < 4; ++it)                                            \
            glds16(gA0 + (size_t)((cnb) * 32 + it * 8) * DD,                      \
                   &Mlb[(bsel)][ldsOff + it * 2048]);                             \
        _Pragma("unroll")                                                         \
        for (int it = 0; it < 4; ++it)                                            \
            glds16(gB0 + (size_t)it * 64 * kdim + (cnb) * 32,                     \
                   &Mtb[(bsel)][ldsOff + it * 2048]);                             \
    }

    STAGE(0, 0);
    __syncthreads();   // drains vmcnt -> chunk 0 staged

    for (int nb = 0; nb < nblk; ++nb) {
        const int p = nb & 1;
        if (nb + 1 < nblk) STAGE(p ^ 1, nb + 1);   // async, drains at loop-end barrier

        const char* MlP = (const char*)&Mlb[p][0];
        const char* MtP = (const char*)&Mtb[p][0];

        // scores S[2][16 x 32] = x_tile . M_chunk^T; each b feeds both halves
#pragma unroll
        for (int cc = 0; cc < 2; ++cc) {
            f32x4 s0 = (f32x4){0.f,0.f,0.f,0.f};
            f32x4 s1 = (f32x4){0.f,0.f,0.f,0.f};
            const char* rowp = MlP + (size_t)(cc * 16 + l16) * 512;
#pragma unroll
            for (int ds = 0; ds < 8; ++ds) {
                bf16x8 b = *(const bf16x8*)(rowp + ((ds * 64 + quad * 16) ^ xorA));
                s0 = __builtin_amdgcn_mfma_f32_16x16x32_bf16(afrag[0][ds], b, s0, 0, 0, 0);
                s1 = __builtin_amdgcn_mfma_f32_16x16x32_bf16(afrag[1][ds], b, s1, 0, 0, 0);
            }
#pragma unroll
            for (int rg = 0; rg < 4; ++rg) {
                float p0 = __expf(s0[rg]);
                float p1 = __expf(s1[rg]);
                lsum[0][rg] += p0;
                lsum[1][rg] += p1;
                Pl[wave][0][quad * 4 + rg][cc * 16 + l16] = f2bf(p0);
                Pl[wave][1][quad * 4 + rg][cc * 16 + l16] = f2bf(p1);
            }
        }
        // wave-private handoff: Pl is wave-indexed; lgkmcnt does NOT wait the glds (vmcnt)
        asm volatile("s_waitcnt lgkmcnt(0)" ::: "memory");
        __builtin_amdgcn_sched_barrier(0);
        bf16x8 pa0 = *(const bf16x8*)&Pl[wave][0][l16][quad * 8];
        bf16x8 pa1 = *(const bf16x8*)&Pl[wave][1][l16][quad * 8];
        // O += P[16x32] . M_chunk[32x256]; each b feeds both halves
#pragma unroll
        for (int f = 0; f < 16; ++f) {
            bf16x8 b = *(const bf16x8*)(MtP + (size_t)(f * 16 + l16) * 64 + ((quad * 16) ^ xorB));
            O0[f] = __builtin_amdgcn_mfma_f32_16x16x32_bf16(pa0, b, O0[f], 0, 0, 0);
            O1[f] = __builtin_amdgcn_mfma_f32_16x16x32_bf16(pa1, b, O1[f], 0, 0, 0);
        }

        __syncthreads();   // implicit vmcnt(0)+lgkmcnt(0) drain: next chunk staged & readers done
    }
#undef STAGE

    // ---- epilogue per half: denom reduce + blend + LayerNorm (row-local, in-place safe) ----
    float gcol[16], bcol[16];
#pragma unroll
    for (int f = 0; f < 16; ++f) {
        gcol[f] = gf[f * 16 + l16];
        bcol[f] = bfa[f * 16 + l16];
    }
#pragma unroll
    for (int h = 0; h < 2; ++h) {
        float l_r[4];
#pragma unroll
        for (int rg = 0; rg < 4; ++rg) {
            float v = lsum[h][rg];
#pragma unroll
            for (int off = 1; off < 16; off <<= 1) v += __shfl_xor(v, off);
            l_r[rg] = v;
        }
#pragma unroll
        for (int rg = 0; rg < 4; ++rg) {
            int grow = base_row + h * 64 + wave * 16 + quad * 4 + rg;
            if (grow < nrows) {
                float inv = 1.0f / l_r[rg];
                float dr  = dinv[grow];
                const ushort* xp = x   + (size_t)grow * DD;
                const ushort* ap = agg + (size_t)grow * DD;
                float xn[16];
                float s = 0.0f;
#pragma unroll
                for (int f = 0; f < 16; ++f) {
                    float xr  = bf2f(xp[f * 16 + l16]);
                    float ag  = bf2f(ap[f * 16 + l16]);
                    float rv  = (h ? O1[f][rg] : O0[f][rg]) * inv;
                    float lap = xr - dr * ag;                     // x - D^-1/2 A D^-1/2 x
                    float v   = 0.5f * xr + 0.5f * (rv - 0.2f * lap);
                    xn[f] = v;
                    s += v;
                }
#pragma unroll
                for (int off = 1; off < 16; off <<= 1) s += __shfl_xor(s, off);
                float mu = s * (1.0f / 256.0f);
                float vs = 0.0f;
#pragma unroll
                for (int f = 0; f < 16; ++f) { float d = xn[f] - mu; vs += d * d; }
#pragma unroll
                for (int off = 1; off < 16; off <<= 1) vs += __shfl_xor(vs, off);
                float rstd = rsqrtf(vs * (1.0f / 256.0f) + 1e-5f);
                if (write_f32) {
                    float* op = (float*)out + (size_t)grow * DD;
#pragma unroll
                    for (int f = 0; f < 16; ++f)
                        op[f * 16 + l16] = (xn[f] - mu) * rstd * gcol[f] + bcol[f];
                } else {
                    ushort* op = (ushort*)out + (size_t)grow * DD;
#pragma unroll
                    for (int f = 0; f < 16; ++f)
                        op[f * 16 + l16] = f2bf((xn[f] - mu) * rstd * gcol[f] + bcol[f]);
                }
            }
        }
    }
}

// ------------------ launch ------------------
extern "C" void kernel_launch(void* const* d_in, const int* in_sizes, int n_in,
                              void* d_out, int out_size, void* d_ws, size_t ws_size,
                              hipStream_t stream)
{
    const void* x_raw = d_in[0];
    const int*  ei    = (const int*)d_in[1];
    const void* M_raw = d_in[2];
    const void* g_raw = d_in[3];
    const void* b_raw = d_in[4];

    const int N_ = in_sizes[0] / DD;
    const int E_ = in_sizes[1] / 2;
    const int K_ = in_sizes[2] / DD;
    const int NB_ = (N_ + BROWS - 1) >> BSHIFT;

    char* w = (char*)d_ws;
    size_t off = 0;
    auto alloc = [&](size_t bytes) -> char* {
        char* p = w + off;
        off = (off + bytes + 255) & ~(size_t)255;
        return p;
    };
    ushort* xbf     = (ushort*)alloc((size_t)N_ * DD * 2);   // 51.2 MB
    ushort* agg     = (ushort*)alloc((size_t)N_ * DD * 2);   // 51.2 MB
    int*    csr     = (int*)   alloc((size_t)E_ * 4);        // 12.8 MB
    ushort* Mbf     = (ushort*)alloc((size_t)K_ * DD * 2);
    ushort* Mt      = (ushort*)alloc((size_t)K_ * DD * 2);
    float*  dinv    = (float*) alloc((size_t)N_ * 4);
    int*    colcnt  = (int*)   alloc((size_t)N_ * 4);
    int*    rowptr  = (int*)   alloc((size_t)(N_ + 1) * 4);
    float*  gf      = (float*) alloc((size_t)DD * 4);
    float*  bfa     = (float*) alloc((size_t)DD * 4);
    int*    flags   = (int*)   alloc(256);
    int*    bkt_cnt = (int*)   alloc((size_t)NBMAX * 4);
    int*    bbase   = (int*)   alloc((size_t)(NBMAX + 1) * 4);
    int*    gcur    = (int*)   alloc((size_t)NBMAX * 4);

    // pairs buffer (E*8B = 25.6MB) overlays agg (51.2MB): agg is dead until
    // lap_kernel, which runs after place_kernel completes (same stream).
    uint2* pairs = (uint2*)agg;

    hipMemsetAsync(colcnt, 0, (size_t)N_ * 4, stream);
    hipMemsetAsync(bkt_cnt, 0, (size_t)NBMAX * 4, stream);

    detect_kernel<<<1, 256, 0, stream>>>((const ushort*)x_raw, ei, flags);

    int nx = N_ * DD, nm = K_ * DD;
    conv_bf_kernel<<<(nx + 255) / 256, 256, 0, stream>>>(x_raw, xbf, nx, flags);
    conv_bf_kernel<<<(nm + 255) / 256, 256, 0, stream>>>(M_raw, Mbf, nm, flags);
    conv_f32_kernel<<<1, 256, 0, stream>>>(g_raw, gf, DD, flags);
    conv_f32_kernel<<<1, 256, 0, stream>>>(b_raw, bfa, DD, flags);
    transpose_kernel<<<(nm + 255) / 256, 256, 0, stream>>>(Mbf, Mt, K_);

    int gA = (E_ + 4095) / 4096;
    int gN = (N_ + 255) / 256;
    countA_kernel<<<gA, 256, 0, stream>>>(ei, E_, N_, colcnt, bkt_cnt, flags);
    dinv_kernel<<<gN, 256, 0, stream>>>(colcnt, dinv, N_);
    bscan_kernel<<<1, NBMAX, 0, stream>>>(bkt_cnt, bbase, gcur, NB_);
    partition_kernel<<<gA, 256, 0, stream>>>(ei, E_, N_, gcur, pairs, flags);
    place_kernel<<<NB_, 1024, 0, stream>>>(pairs, bbase, NB_, N_, E_, rowptr, csr);

    int attnBlocks = (N_ + 127) / 128;
    // iteration 1: xbf -> xbf (in place; attention is row-local)
    lap_kernel<<<N_, 256, 0, stream>>>(xbf, rowptr, csr, dinv, agg, N_);
    attn_fused_kernel<<<attnBlocks, 256, 0, stream>>>(xbf, Mbf, Mt, agg, dinv, gf, bfa,
                                                      (void*)xbf, N_, K_, 0, flags);
    // iteration 2: xbf -> d_out (final dtype per flag)
    lap_kernel<<<N_, 256, 0, stream>>>(xbf, rowptr, csr, dinv, agg, N_);
    attn_fused_kernel<<<attnBlocks, 256, 0, stream>>>(xbf, Mbf, Mt, agg, dinv, gf, bfa,
                                                      d_out, N_, K_, 1, flags);
}